// Round 17
// baseline (894.679 us; speedup 1.0000x reference)
//
#include <hip/hip_runtime.h>

#define HID  64
#define SEQT 1024
#define NB   2

typedef _Float16 h8 __attribute__((ext_vector_type(8)));
typedef float    f4 __attribute__((ext_vector_type(4)));
typedef float    v2f __attribute__((ext_vector_type(2)));

__device__ __forceinline__ float rcpf(float x){ return __builtin_amdgcn_rcpf(x); }
__device__ __forceinline__ float sigm(float x){ return rcpf(1.0f + __expf(-x)); }
__device__ __forceinline__ float tanh_fast(float x){
    // 1 - 2/(e^{2x}+1); correct saturation at +-inf
    return 1.0f - 2.0f * rcpf(__expf(2.0f * x) + 1.0f);
}
__device__ __forceinline__ v2f pkfma(v2f a, v2f b, v2f c){
    return __builtin_elementwise_fma(a, b, c);      // -> v_pk_fma_f32
}

#define MFMA16(A,B,C) __builtin_amdgcn_mfma_f32_16x16x32_f16((A),(B),(C),0,0,0)

// round 8 fp32 values to f16 (1-term weights)
__device__ __forceinline__ h8 cvt8(const float* __restrict__ p) {
    float4 u = *(const float4*)p;
    float4 v = *(const float4*)(p + 4);
    h8 r;
    r[0] = (_Float16)u.x; r[1] = (_Float16)u.y;
    r[2] = (_Float16)u.z; r[3] = (_Float16)u.w;
    r[4] = (_Float16)v.x; r[5] = (_Float16)v.y;
    r[6] = (_Float16)v.z; r[7] = (_Float16)v.w;
    return r;
}

// v16 math/schedule split into TWO desynchronized barrier domains per CU:
// NB=2 batches/block, 512 thr = 8 waves, 512 blocks -> exactly 2 blocks/CU
// (HW-enforced: 16 waves/CU at <=128 VGPR). s_barrier is per-workgroup, so
// when block A's cell wave sits in its serial trans chain (~350 cy, the v16
// phase-span driver), block B's MFMA fills the matrix pipe. Per-CU cell/VALU
// totals unchanged; MFMA/SIMD doubles to 48/iter (931 cy floor) because NB=2
// halves column utilization — the wager is dead-time overlap > extra MFMA.
// Wave m owns tiles {2m,2m+1}; phase-interleaved v15 schedule:
//   Phase A: G0(t) [2 chains x2 MFMA] || cell1(t-2) waves 2-3; barrier
//   Phase B: G1(t-1) [2 chains x4]    || cell0(t)   waves 0-1; barrier
// 1-term f16 weights, f16-exact h state (absmax 1.22e-4 proven), G single-
// buffered, h parity double-buffered, peeled x2 unroll, setprio on MFMA.
__global__ __launch_bounds__(512, 4)
void lstm2_v17(const float* __restrict__ x,
               const float* __restrict__ W_ih0, const float* __restrict__ W_hh0,
               const float* __restrict__ b_ih0, const float* __restrict__ b_hh0,
               const float* __restrict__ W_ih1, const float* __restrict__ W_hh1,
               const float* __restrict__ b_ih1, const float* __restrict__ b_hh1,
               const float* __restrict__ fc1_w, const float* __restrict__ fc1_b,
               const float* __restrict__ fc2_w, const float* __restrict__ fc2_b,
               float* __restrict__ out, int nblk)
{
    const int blk = blockIdx.x;
    if (blk >= nblk) return;
    const int tid = threadIdx.x;
    const int w   = tid >> 6;          // wave 0..7: owns tiles {2w, 2w+1}
    const int l   = tid & 63;          // lane
    const int r16 = l & 15;            // A row in tile / D col (batch)
    const int g4  = l >> 4;            // k-subgroup / D row group
    const int cc  = r16 & 1;           // batch col (cols replicated x8)
    const int B0  = blk * NB;

    // ---------------- LDS ----------------
    __shared__ __align__(16) _Float16 h1f[2][NB][80];   // f16-exact h1
    __shared__ __align__(16) _Float16 h2f16[2][NB][80]; // f16-exact h2
    __shared__ __align__(16) float G0[NB][260];
    __shared__ __align__(16) float G1[NB][260];
    __shared__ __align__(16) float h2fin[NB][64];

    // ---------------- A-fragments: tiles 2w,2w+1 (rows 32w+16tt+r16) --------
    h8 a0[2][2];   // [tile][ks]  W_hh0
    h8 a1[2][4];   // [tile][ks]  ks 0,1: W_ih1 ; ks 2,3: W_hh1
    #pragma unroll
    for (int tt = 0; tt < 2; ++tt) {
        const int row = 32 * w + 16 * tt + r16;
        #pragma unroll
        for (int ks = 0; ks < 2; ++ks) {
            a0[tt][ks]     = cvt8(W_hh0 + row * HID + ks * 32 + g4 * 8);
            a1[tt][ks]     = cvt8(W_ih1 + row * HID + ks * 32 + g4 * 8);
            a1[tt][2 + ks] = cvt8(W_hh1 + row * HID + ks * 32 + g4 * 8);
        }
    }

    // ---------------- cell constants, packed v2f ----------------------------
    // waves 0-1: cell0 (batch w); waves 2-3: cell1 (batch w-2)
    const bool meC0 = (w < 2);
    const bool meC1 = (w >= 2 && w < 4);
    const int  cb   = meC0 ? w : (w - 2);
    const float* bip = meC0 ? b_ih0 : b_ih1;
    const float* bhp = meC0 ? b_hh0 : b_hh1;
    v2f biasA, biasB, wihA, wihB;
    biasA.x = bip[l]       + bhp[l];
    biasA.y = bip[l + 64]  + bhp[l + 64];
    biasB.x = bip[l + 128] + bhp[l + 128];
    biasB.y = bip[l + 192] + bhp[l + 192];
    if (meC0) {
        wihA.x = W_ih0[l];       wihA.y = W_ih0[l + 64];
        wihB.x = W_ih0[l + 128]; wihB.y = W_ih0[l + 192];
    } else {
        wihA = (v2f){0.f, 0.f};  wihB = (v2f){0.f, 0.f};
    }

    // ---------------- init ----------------
    if (tid < 160) {   // 160 ints = 2*NB*80 halves per array
        ((int*)h1f)[tid] = 0; ((int*)h2f16)[tid] = 0;
    }
    const size_t xbase = (size_t)(B0 + cb) * SEQT;
    float xc = 0.0f, xcn = 0.0f;
    if (meC0) xc = x[xbase + l];       // chunk for t = 0..63 (lane = t offset)
    float cst = 0.0f;                  // c1 (waves 0-1) / c2 (waves 2-3)
    __syncthreads();

    const f4 z4 = {0.f, 0.f, 0.f, 0.f};

    // one interleaved iteration; P = t&1 compile-time at every call site
    auto step = [&](int t_, int P,
                    bool L0A, bool G1A, bool C0A, bool C1A, bool FIN) {
        const int RB1 = P ^ 1;         // buf of h1(t-1)

        // ================= Phase A: G0(t) MFMA || cell1(t-2) =================
        if (meC0 && ((t_ & 63) == 0) && (t_ + 64 < SEQT))
            xcn = x[xbase + t_ + 64 + l];

        // b1 frags: live across the barrier into Phase B (buf untouched there)
        h8 b1h0, b1h1;
        if (L0A || G1A) {
            b1h0 = *(const h8*)&h1f[RB1][cc][g4 * 8];
            b1h1 = *(const h8*)&h1f[RB1][cc][32 + g4 * 8];
        }
        // cell1's G-reads issue before the MFMA cluster (latency hides under it)
        v2f gA1, gB1;
        if (C1A && meC1) {
            gA1 = (v2f){G1[cb][l],       G1[cb][l + 64]};
            gB1 = (v2f){G1[cb][l + 128], G1[cb][l + 192]};
        }
        __builtin_amdgcn_s_setprio(1);
        if (L0A) {   // G0(t) = Whh0 * h1(t-1): 2 chains, depth 2
            f4 e0 = MFMA16(a0[0][0], b1h0, z4);
            f4 e1 = MFMA16(a0[1][0], b1h0, z4);
            e0 = MFMA16(a0[0][1], b1h1, e0);
            e1 = MFMA16(a0[1][1], b1h1, e1);
            if (r16 < NB) {
                *(f4*)&G0[r16][32 * w + 4 * g4]      = e0;
                *(f4*)&G0[r16][32 * w + 16 + 4 * g4] = e1;
            }
        }
        __builtin_amdgcn_s_setprio(0);
        if (C1A && meC1) {             // cell1(t-2), batch cb
            v2f pA = gA1 + biasA;
            v2f pB = gB1 + biasB;
            float iv = sigm(pA.x), fv = sigm(pA.y);
            float gv = tanh_fast(pB.x), ov = sigm(pB.y);
            cst = fmaf(fv, cst, iv * gv);
            float hv = ov * tanh_fast(cst);
            _Float16 hh = (_Float16)hv;
            h2f16[P][cb][l] = hh;      // h2(t-2) -> buf (t-2)&1 == P
            if (FIN) h2fin[cb][l] = (float)hh;
        }
        __syncthreads();               // G0(t), h2(t-2) visible

        // ================= Phase B: G1(t-1) MFMA || cell0(t) =================
        v2f gA0, gB0;
        if (C0A && meC0) {
            gA0 = (v2f){G0[cb][l],       G0[cb][l + 64]};
            gB0 = (v2f){G0[cb][l + 128], G0[cb][l + 192]};
        }
        __builtin_amdgcn_s_setprio(1);
        if (G1A) {   // G1(t-1) = Wih1*h1(t-1) + Whh1*h2(t-2): 2 chains, depth 4
            h8 b2h0 = *(const h8*)&h2f16[P][cc][g4 * 8];
            h8 b2h1 = *(const h8*)&h2f16[P][cc][32 + g4 * 8];
            f4 p0 = MFMA16(a1[0][0], b1h0, z4);
            f4 p1 = MFMA16(a1[1][0], b1h0, z4);
            p0 = MFMA16(a1[0][1], b1h1, p0);
            p1 = MFMA16(a1[1][1], b1h1, p1);
            p0 = MFMA16(a1[0][2], b2h0, p0);
            p1 = MFMA16(a1[1][2], b2h0, p1);
            p0 = MFMA16(a1[0][3], b2h1, p0);
            p1 = MFMA16(a1[1][3], b2h1, p1);
            if (r16 < NB) {
                *(f4*)&G1[r16][32 * w + 4 * g4]      = p0;
                *(f4*)&G1[r16][32 * w + 16 + 4 * g4] = p1;
            }
        }
        __builtin_amdgcn_s_setprio(0);
        if (C0A && meC0) {             // cell0(t), batch cb
            const float xt = __shfl(xc, t_ & 63);
            v2f xt2 = {xt, xt};
            v2f pA = gA0 + pkfma(xt2, wihA, biasA);
            v2f pB = gB0 + pkfma(xt2, wihB, biasB);
            float iv = sigm(pA.x), fv = sigm(pA.y);
            float gv = tanh_fast(pB.x), ov = sigm(pB.y);
            cst = fmaf(fv, cst, iv * gv);
            float hv = ov * tanh_fast(cst);
            h1f[P][cb][l] = (_Float16)hv;   // h1(t) -> buf t&1 == P
        }
        if ((t_ & 63) == 63) xc = xcn;
        __syncthreads();               // G1(t-1), h1(t) visible
    };

    //            t    P  L0A    G1A    C0A    C1A    FIN
    step(        0,    0, true,  false, true,  false, false);
    step(        1,    1, true,  true,  true,  false, false);
    #pragma unroll 1
    for (int t = 2; t < SEQT; t += 2) {
        step(t,      0, true,  true,  true,  true,  false);
        step(t + 1,  1, true,  true,  true,  true,  false);
    }
    step(     SEQT,    0, false, true,  false, true,  false);
    step( SEQT + 1,    1, false, false, false, true,  true );

    // ---------------- FC head: waves 0-1 -> batches 0-1 ----------------
    if (w < 2) {
        float z = 0.0f;
        if (l < 32) {
            float acc = fc1_b[l];
            const f4* hvp = (const f4*)h2fin[w];
            const f4* wvp = (const f4*)(fc1_w + l * HID);
            #pragma unroll
            for (int q = 0; q < 16; ++q) {
                f4 hq = hvp[q], wk = wvp[q];
                acc = fmaf(hq[0], wk[0], acc); acc = fmaf(hq[1], wk[1], acc);
                acc = fmaf(hq[2], wk[2], acc); acc = fmaf(hq[3], wk[3], acc);
            }
            z = fmaxf(acc, 0.0f) * fc2_w[l];
        }
        #pragma unroll
        for (int off = 32; off > 0; off >>= 1) z += __shfl_xor(z, off);
        if (l == 0) out[B0 + w] = z + fc2_b[0];
    }
}

extern "C" void kernel_launch(void* const* d_in, const int* in_sizes, int n_in,
                              void* d_out, int out_size, void* d_ws, size_t ws_size,
                              hipStream_t stream) {
    const float* x     = (const float*)d_in[0];
    const float* W_ih0 = (const float*)d_in[1];
    const float* W_hh0 = (const float*)d_in[2];
    const float* b_ih0 = (const float*)d_in[3];
    const float* b_hh0 = (const float*)d_in[4];
    const float* W_ih1 = (const float*)d_in[5];
    const float* W_hh1 = (const float*)d_in[6];
    const float* b_ih1 = (const float*)d_in[7];
    const float* b_hh1 = (const float*)d_in[8];
    const float* fc1_w = (const float*)d_in[9];
    const float* fc1_b = (const float*)d_in[10];
    const float* fc2_w = (const float*)d_in[11];
    const float* fc2_b = (const float*)d_in[12];
    float* out = (float*)d_out;

    const int batch = in_sizes[0] / SEQT;   // 1024
    const int nblk  = batch / NB;           // 512 blocks -> 2 per CU
    dim3 grid(nblk), block(512);
    hipLaunchKernelGGL(lstm2_v17, grid, block, 0, stream,
                       x, W_ih0, W_hh0, b_ih0, b_hh0,
                       W_ih1, W_hh1, b_ih1, b_hh1,
                       fc1_w, fc1_b, fc2_w, fc2_b, out, nblk);
}

// Round 18
// 497.425 us; speedup vs baseline: 1.7986x; 1.7986x over previous
//
#include <hip/hip_runtime.h>

#define HID  64
#define SEQT 1024
#define NB   4

typedef _Float16 h8 __attribute__((ext_vector_type(8)));
typedef float    f4 __attribute__((ext_vector_type(4)));
typedef float    v2f __attribute__((ext_vector_type(2)));

__device__ __forceinline__ float rcpf(float x){ return __builtin_amdgcn_rcpf(x); }
__device__ __forceinline__ float sigm(float x){ return rcpf(1.0f + __expf(-x)); }
__device__ __forceinline__ float tanh_fast(float x){
    // 1 - 2/(e^{2x}+1); correct saturation at +-inf
    return 1.0f - 2.0f * rcpf(__expf(2.0f * x) + 1.0f);
}
__device__ __forceinline__ v2f pkfma(v2f a, v2f b, v2f c){
    return __builtin_elementwise_fma(a, b, c);      // -> v_pk_fma_f32
}

#define MFMA16(A,B,C) __builtin_amdgcn_mfma_f32_16x16x32_f16((A),(B),(C),0,0,0)

// round 8 fp32 values to f16 (1-term weights)
__device__ __forceinline__ h8 cvt8(const float* __restrict__ p) {
    float4 u = *(const float4*)p;
    float4 v = *(const float4*)(p + 4);
    h8 r;
    r[0] = (_Float16)u.x; r[1] = (_Float16)u.y;
    r[2] = (_Float16)u.z; r[3] = (_Float16)u.w;
    r[4] = (_Float16)v.x; r[5] = (_Float16)v.y;
    r[6] = (_Float16)v.z; r[7] = (_Float16)v.w;
    return r;
}

// v16 math/partition (NB=4, 24 MFMA/SIMD/iter floor, 1-term f16 weights,
// f16-exact h) with WAVE SPECIALIZATION + L1 phase-split:
//   waves 0-3: pure MFMA. Wave j owns tiles {j, 4+j, 8+j, 12+j}.
//     Phase A: L0(t) 4 chains x2  +  L1(t-1) h1-half partials 4 chains x2
//     Phase B: L1(t-1) h2-half 4 chains x2 (C-chained onto partials) -> G1
//   waves 4-7: pure cell. Wave 4+b owns batch b.
//     Phase A: cell1(t-2)  [reads G1 written in B(t-1), barrier-ordered]
//     Phase B: cell0(t)    [reads G0 written in A(t)]
// Each SIMD hosts 1 MFMA wave + 1 cell wave: the cell's G-read + serial
// trans chain starts immediately post-barrier and co-issues with the MFMA
// wave's matrix ops (separate pipes, m114). L1 split balances the matrix
// pipe 16/8 across phases; partials ride registers across the barrier.
// Dataflow (barrier-ordered, race-free):
//   G0: written A(t), read B(t).  G1: written B(t), read A(t+1).
//   h1(t): cell0 B(t) -> buf t&1; read A/B(t+1) from buf t&1.
//   h2(t-2): cell1 A(t) -> buf t&1; read B(t) (L1 h2-half) from buf t&1.
__global__ __launch_bounds__(512, 2)
void lstm2_v18(const float* __restrict__ x,
               const float* __restrict__ W_ih0, const float* __restrict__ W_hh0,
               const float* __restrict__ b_ih0, const float* __restrict__ b_hh0,
               const float* __restrict__ W_ih1, const float* __restrict__ W_hh1,
               const float* __restrict__ b_ih1, const float* __restrict__ b_hh1,
               const float* __restrict__ fc1_w, const float* __restrict__ fc1_b,
               const float* __restrict__ fc2_w, const float* __restrict__ fc2_b,
               float* __restrict__ out, int nblk)
{
    const int blk = blockIdx.x;
    if (blk >= nblk) return;
    const int tid = threadIdx.x;
    const int w   = tid >> 6;          // wave 0..7
    const int l   = tid & 63;          // lane
    const int r16 = l & 15;            // A row in tile / D col (batch)
    const int g4  = l >> 4;            // k-subgroup / D row group
    const int cc  = r16 & 3;           // batch col for B-frag broadcast
    const bool isCell = (w >= 4);
    const int cb  = w & 3;             // cell batch (cell waves)
    const int B0  = blk * NB;

    // ---------------- LDS ----------------
    __shared__ __align__(16) _Float16 h1f[2][NB][80];   // f16-exact h1
    __shared__ __align__(16) _Float16 h2f16[2][NB][80]; // f16-exact h2
    __shared__ __align__(16) float G0[NB][260];
    __shared__ __align__(16) float G1[NB][260];
    __shared__ __align__(16) float h2fin[NB][64];

    // ---------------- A-fragments (MFMA waves): tiles w+4tt ----------------
    h8 a0[4][2];   // [tile][ks]  W_hh0
    h8 a1[4][4];   // [tile][ks]  ks 0,1: W_ih1 ; ks 2,3: W_hh1
    if (!isCell) {
        #pragma unroll
        for (int tt = 0; tt < 4; ++tt) {
            const int row = 16 * (w + 4 * tt) + r16;
            #pragma unroll
            for (int ks = 0; ks < 2; ++ks) {
                a0[tt][ks]     = cvt8(W_hh0 + row * HID + ks * 32 + g4 * 8);
                a1[tt][ks]     = cvt8(W_ih1 + row * HID + ks * 32 + g4 * 8);
                a1[tt][2 + ks] = cvt8(W_hh1 + row * HID + ks * 32 + g4 * 8);
            }
        }
    }

    // ---------------- cell constants (cell waves), packed v2f ---------------
    v2f bias0A, bias0B, bias1A, bias1B, wihA, wihB;
    if (isCell) {
        bias0A.x = b_ih0[l]       + b_hh0[l];
        bias0A.y = b_ih0[l + 64]  + b_hh0[l + 64];
        bias0B.x = b_ih0[l + 128] + b_hh0[l + 128];
        bias0B.y = b_ih0[l + 192] + b_hh0[l + 192];
        bias1A.x = b_ih1[l]       + b_hh1[l];
        bias1A.y = b_ih1[l + 64]  + b_hh1[l + 64];
        bias1B.x = b_ih1[l + 128] + b_hh1[l + 128];
        bias1B.y = b_ih1[l + 192] + b_hh1[l + 192];
        wihA.x = W_ih0[l];       wihA.y = W_ih0[l + 64];
        wihB.x = W_ih0[l + 128]; wihB.y = W_ih0[l + 192];
    }

    // ---------------- init ----------------
    if (tid < 320) {   // 320 ints = 2*NB*80 halves per array
        ((int*)h1f)[tid] = 0; ((int*)h2f16)[tid] = 0;
    }
    const size_t xbase = (size_t)(B0 + cb) * SEQT;
    float xc = 0.0f, xcn = 0.0f;
    if (isCell) xc = x[xbase + l];     // chunk for t = 0..63 (lane = t offset)
    float c1 = 0.0f, c2 = 0.0f;        // both cells live on the cell wave
    __syncthreads();

    const f4 z4 = {0.f, 0.f, 0.f, 0.f};

    // one iteration; P = t&1 compile-time at every call site
    auto step = [&](int t_, int P,
                    bool L0A, bool G1A, bool C0A, bool C1A, bool FIN) {
        const int RB1 = P ^ 1;         // buf of h1(t-1)
        f4 p0, p1, p2, p3;             // L1 partials, live A -> B

        // ================= Phase A =================
        if (isCell) {
            if (((t_ & 63) == 0) && (t_ + 64 < SEQT))
                xcn = x[xbase + t_ + 64 + l];
            if (C1A) {                 // cell1(t-2), batch cb
                v2f gA = {G1[cb][l],       G1[cb][l + 64]};
                v2f gB = {G1[cb][l + 128], G1[cb][l + 192]};
                v2f pA = gA + bias1A;
                v2f pB = gB + bias1B;
                float iv = sigm(pA.x), fv = sigm(pA.y);
                float gv = tanh_fast(pB.x), ov = sigm(pB.y);
                c2 = fmaf(fv, c2, iv * gv);
                float hv = ov * tanh_fast(c2);
                _Float16 hh = (_Float16)hv;
                h2f16[P][cb][l] = hh;  // h2(t-2) -> buf (t-2)&1 == P
                if (FIN) h2fin[cb][l] = (float)hh;
            }
        } else {
            h8 b1h0, b1h1;
            if (L0A || G1A) {
                b1h0 = *(const h8*)&h1f[RB1][cc][g4 * 8];
                b1h1 = *(const h8*)&h1f[RB1][cc][32 + g4 * 8];
            }
            __builtin_amdgcn_s_setprio(1);
            if (L0A) {                 // L0(t): 4 chains depth 2 -> G0
                f4 e0 = MFMA16(a0[0][0], b1h0, z4);
                f4 e1 = MFMA16(a0[1][0], b1h0, z4);
                f4 e2 = MFMA16(a0[2][0], b1h0, z4);
                f4 e3 = MFMA16(a0[3][0], b1h0, z4);
                e0 = MFMA16(a0[0][1], b1h1, e0);
                e1 = MFMA16(a0[1][1], b1h1, e1);
                e2 = MFMA16(a0[2][1], b1h1, e2);
                e3 = MFMA16(a0[3][1], b1h1, e3);
                if (r16 < NB) {
                    *(f4*)&G0[r16][16 * w + 4 * g4]       = e0;
                    *(f4*)&G0[r16][16 * w + 64 + 4 * g4]  = e1;
                    *(f4*)&G0[r16][16 * w + 128 + 4 * g4] = e2;
                    *(f4*)&G0[r16][16 * w + 192 + 4 * g4] = e3;
                }
            }
            if (G1A) {                 // L1(t-1) h1-half: 4 chains depth 2
                p0 = MFMA16(a1[0][0], b1h0, z4);
                p1 = MFMA16(a1[1][0], b1h0, z4);
                p2 = MFMA16(a1[2][0], b1h0, z4);
                p3 = MFMA16(a1[3][0], b1h0, z4);
                p0 = MFMA16(a1[0][1], b1h1, p0);
                p1 = MFMA16(a1[1][1], b1h1, p1);
                p2 = MFMA16(a1[2][1], b1h1, p2);
                p3 = MFMA16(a1[3][1], b1h1, p3);
            }
            __builtin_amdgcn_s_setprio(0);
        }
        __syncthreads();               // G0(t), h2(t-2) visible

        // ================= Phase B =================
        if (isCell) {
            if (C0A) {                 // cell0(t), batch cb
                v2f gA = {G0[cb][l],       G0[cb][l + 64]};
                v2f gB = {G0[cb][l + 128], G0[cb][l + 192]};
                const float xt = __shfl(xc, t_ & 63);
                v2f xt2 = {xt, xt};
                v2f pA = gA + pkfma(xt2, wihA, bias0A);
                v2f pB = gB + pkfma(xt2, wihB, bias0B);
                float iv = sigm(pA.x), fv = sigm(pA.y);
                float gv = tanh_fast(pB.x), ov = sigm(pB.y);
                c1 = fmaf(fv, c1, iv * gv);
                float hv = ov * tanh_fast(c1);
                h1f[P][cb][l] = (_Float16)hv;   // h1(t) -> buf t&1 == P
            }
            if ((t_ & 63) == 63) xc = xcn;
        } else {
            if (G1A) {                 // L1(t-1) h2-half: finish chains -> G1
                h8 b2h0 = *(const h8*)&h2f16[P][cc][g4 * 8];
                h8 b2h1 = *(const h8*)&h2f16[P][cc][32 + g4 * 8];
                __builtin_amdgcn_s_setprio(1);
                p0 = MFMA16(a1[0][2], b2h0, p0);
                p1 = MFMA16(a1[1][2], b2h0, p1);
                p2 = MFMA16(a1[2][2], b2h0, p2);
                p3 = MFMA16(a1[3][2], b2h0, p3);
                p0 = MFMA16(a1[0][3], b2h1, p0);
                p1 = MFMA16(a1[1][3], b2h1, p1);
                p2 = MFMA16(a1[2][3], b2h1, p2);
                p3 = MFMA16(a1[3][3], b2h1, p3);
                __builtin_amdgcn_s_setprio(0);
                if (r16 < NB) {
                    *(f4*)&G1[r16][16 * w + 4 * g4]       = p0;
                    *(f4*)&G1[r16][16 * w + 64 + 4 * g4]  = p1;
                    *(f4*)&G1[r16][16 * w + 128 + 4 * g4] = p2;
                    *(f4*)&G1[r16][16 * w + 192 + 4 * g4] = p3;
                }
            }
        }
        __syncthreads();               // G1(t-1), h1(t) visible
    };

    //            t    P  L0A    G1A    C0A    C1A    FIN
    step(        0,    0, true,  false, true,  false, false);
    step(        1,    1, true,  true,  true,  false, false);
    #pragma unroll 1
    for (int t = 2; t < SEQT; t += 2) {
        step(t,      0, true,  true,  true,  true,  false);
        step(t + 1,  1, true,  true,  true,  true,  false);
    }
    step(     SEQT,    0, false, true,  false, true,  false);
    step( SEQT + 1,    1, false, false, false, true,  true );

    // ---------------- FC head: waves 0-3 -> batch w ----------------
    if (w < 4) {
        float z = 0.0f;
        if (l < 32) {
            float acc = fc1_b[l];
            const f4* hvp = (const f4*)h2fin[w];
            const f4* wvp = (const f4*)(fc1_w + l * HID);
            #pragma unroll
            for (int q = 0; q < 16; ++q) {
                f4 hq = hvp[q], wk = wvp[q];
                acc = fmaf(hq[0], wk[0], acc); acc = fmaf(hq[1], wk[1], acc);
                acc = fmaf(hq[2], wk[2], acc); acc = fmaf(hq[3], wk[3], acc);
            }
            z = fmaxf(acc, 0.0f) * fc2_w[l];
        }
        #pragma unroll
        for (int off = 32; off > 0; off >>= 1) z += __shfl_xor(z, off);
        if (l == 0) out[B0 + w] = z + fc2_b[0];
    }
}

extern "C" void kernel_launch(void* const* d_in, const int* in_sizes, int n_in,
                              void* d_out, int out_size, void* d_ws, size_t ws_size,
                              hipStream_t stream) {
    const float* x     = (const float*)d_in[0];
    const float* W_ih0 = (const float*)d_in[1];
    const float* W_hh0 = (const float*)d_in[2];
    const float* b_ih0 = (const float*)d_in[3];
    const float* b_hh0 = (const float*)d_in[4];
    const float* W_ih1 = (const float*)d_in[5];
    const float* W_hh1 = (const float*)d_in[6];
    const float* b_ih1 = (const float*)d_in[7];
    const float* b_hh1 = (const float*)d_in[8];
    const float* fc1_w = (const float*)d_in[9];
    const float* fc1_b = (const float*)d_in[10];
    const float* fc2_w = (const float*)d_in[11];
    const float* fc2_b = (const float*)d_in[12];
    float* out = (float*)d_out;

    const int batch = in_sizes[0] / SEQT;   // 1024
    const int nblk  = batch / NB;           // 256 blocks, 1 per CU
    dim3 grid(nblk), block(512);
    hipLaunchKernelGGL(lstm2_v18, grid, block, 0, stream,
                       x, W_ih0, W_hh0, b_ih0, b_hh0,
                       W_ih1, W_hh1, b_ih1, b_hh1,
                       fc1_w, fc1_b, fc2_w, fc2_b, out, nblk);
}